// Round 5
// baseline (234.689 us; speedup 1.0000x reference)
//
#include <hip/hip_runtime.h>
#include <hip/hip_bf16.h>

// NT-Xent loss, 2B=8192, D=128, T=0.5. Two dispatches:
//  k_prep : row-normalize -> bf16 nb; picked logit per row in fp32;
//           zero l_arr + counter.
//  k_fused: Gram matrix via MFMA with LDS-staged B (global_load_lds w=16),
//           masked exp-sum (fixed max = 2.0 since cos<=1) -> l_arr atomics;
//           last-finishing block reduces 2+ln(l)-picked and writes out.
// Round-5 restructure: wave tile 32x64 with 8 independent MFMA accumulator
// chains (acc0[4]/acc1[4] live across a chunk) + asm-pinned A fragments, to
// fix the ILP starvation (2 chains) and A-rematerialization (VGPR=60)
// diagnosed in rounds 2-4.

typedef __bf16 bf16x8 __attribute__((ext_vector_type(8)));
typedef float floatx4 __attribute__((ext_vector_type(4)));

#define TWO_B 8192
#define B_HALF 4096
#define D 128
#define INV_T 2.0f                 // 1/temperature
#define FIXED_MAX 2.0f             // logit upper bound (cos<=1)
#define C_EXP 2.885390081777927f   // INV_T * log2(e) == FIXED_MAX * log2(e)
#define NSPLIT 16                  // column splits (512 cols each)
#define NROWBLK (TWO_B / 64)       // 128 row blocks (64 rows each)
#define GRID_TOTAL (NROWBLK * NSPLIT)

#if defined(__has_builtin) && __has_builtin(__builtin_amdgcn_exp2f)
#define EXP2F(x) __builtin_amdgcn_exp2f(x)   // raw v_exp_f32; arg in [-5.8, 0]
#else
#define EXP2F(x) exp2f(x)
#endif
#if defined(__has_builtin) && __has_builtin(__builtin_amdgcn_logf)
#define LOG2F(x) __builtin_amdgcn_logf(x)    // raw v_log_f32 (log2)
#else
#define LOG2F(x) log2f(x)
#endif

__device__ inline void load16_lds(const __bf16* g, __bf16* l) {
    __builtin_amdgcn_global_load_lds(
        (const __attribute__((address_space(1))) unsigned int*)g,
        (__attribute__((address_space(3))) unsigned int*)l, 16, 0, 0);
}

// -------- kernel 1: normalize + picked + zero state ----------------------
__global__ void k_prep(const float* __restrict__ emb,
                       const int* __restrict__ labels,
                       __bf16* __restrict__ nb,
                       float* __restrict__ picked,
                       float* __restrict__ l_arr,
                       unsigned int* __restrict__ counter) {
    int wv   = threadIdx.x >> 6;
    int lane = threadIdx.x & 63;
    int i = blockIdx.x * 4 + wv;
    const float2* e2 = reinterpret_cast<const float2*>(emb + (size_t)i * D);
    float2 v = e2[lane];
    float ssi = v.x * v.x + v.y * v.y;
    // picked column: labels[i] skips cols {i, i^4096}
    int p = i ^ B_HALF;
    int a = min(i, p), b = max(i, p);
    int l = labels[i];
    int c = l + (l >= a);
    c += (c >= b);
    const float2* ec2 = reinterpret_cast<const float2*>(emb + (size_t)c * D);
    float2 u = ec2[lane];
    float dot = v.x * u.x + v.y * u.y;
    float ssc = u.x * u.x + u.y * u.y;
#pragma unroll
    for (int off = 32; off >= 1; off >>= 1) {
        ssi += __shfl_xor(ssi, off, 64);
        dot += __shfl_xor(dot, off, 64);
        ssc += __shfl_xor(ssc, off, 64);
    }
    float rn = rsqrtf(fmaxf(ssi, 1e-16f));
    union { __bf16 h[2]; unsigned int uu; } pk;
    pk.h[0] = (__bf16)(v.x * rn);
    pk.h[1] = (__bf16)(v.y * rn);
    reinterpret_cast<unsigned int*>(nb)[i * 64 + lane] = pk.uu;
    if (lane == 0)
        picked[i] = dot / fmaxf(sqrtf(ssi * ssc), 1e-8f) * INV_T;
    if (blockIdx.x < TWO_B / 256) l_arr[blockIdx.x * 256 + threadIdx.x] = 0.f;
    if (blockIdx.x == 0 && threadIdx.x == 0) counter[0] = 0u;
}

// -------- kernel 2: fused Gram MFMA + masked exp-sum + final reduce ------
// grid (128, 16), block 256 = 4 waves. Block tile: 64 rows x 512 cols,
// processed as 4 chunks of 128 cols (B chunk in LDS, fragment order).
// Wave layout: wave w -> rows (w>>1)*32, cols (w&1)*64 of the chunk.
__global__ __launch_bounds__(256, 4) void k_fused(const __bf16* __restrict__ nb,
                                                  float* __restrict__ l_arr,
                                                  const float* __restrict__ picked,
                                                  unsigned int* __restrict__ counter,
                                                  float* __restrict__ out) {
    __shared__ __bf16 lds[16384];            // 32 KB: 128 cols x K=128
    __shared__ float sred[4];
    __shared__ int s_last;

    const int lane = threadIdx.x & 63;
    const int w    = threadIdx.x >> 6;
    const int m    = lane & 15;
    const int quad = lane >> 4;
    const int rowbase = blockIdx.x * 64 + (w >> 1) * 32;  // wave rows: +0..31
    const int colB    = blockIdx.y * 512;                  // block cols
    const int sg0     = (w & 1) * 4;                       // wave's 4 sub-tiles

    // block-uniform: does this tile contain masked (diag/positive) entries?
    const int r0 = blockIdx.x * 64;
    const int pr0 = r0 ^ B_HALF;
    const bool bmask = ((r0 < colB + 512) && (colB < r0 + 64)) ||
                       ((pr0 < colB + 512) && (colB < pr0 + 64));

    // A fragments: two 16-row tiles, full K=128, pinned in registers (32 VGPR)
    bf16x8 a0[4], a1[4];
#pragma unroll
    for (int kc = 0; kc < 4; ++kc) {
        a0[kc] = *reinterpret_cast<const bf16x8*>(
            nb + (size_t)(rowbase + m) * D + kc * 32 + quad * 8);
        a1[kc] = *reinterpret_cast<const bf16x8*>(
            nb + (size_t)(rowbase + 16 + m) * D + kc * 32 + quad * 8);
    }
    // opaque to the register allocator: forbids rematerializing the loads
    asm volatile("" : "+v"(a0[0]), "+v"(a0[1]), "+v"(a0[2]), "+v"(a0[3]),
                      "+v"(a1[0]), "+v"(a1[1]), "+v"(a1[2]), "+v"(a1[3]));

    float l0[4] = {0.f, 0.f, 0.f, 0.f};
    float l1[4] = {0.f, 0.f, 0.f, 0.f};
    const int i0 = rowbase + quad * 4;       // l0 rows; l1 rows = i0+16

    for (int ch = 0; ch < 4; ++ch) {
        const int colbase = colB + ch * 128;
        // ---- stage 128 cols x 128 K into LDS, fragment order -----------
        {
            const __bf16* g = nb + (size_t)(colbase + m) * D + w * 32 + quad * 8;
#pragma unroll
            for (int j = 0; j < 8; ++j)
                load16_lds(g + (size_t)j * 16 * D, &lds[j * 2048 + w * 512]);
        }
        __syncthreads();   // compiler drains vmcnt(0) before barrier

        // ---- MFMA: 8 independent accumulator chains ---------------------
        floatx4 acc0[4] = {{0.f,0.f,0.f,0.f},{0.f,0.f,0.f,0.f},
                           {0.f,0.f,0.f,0.f},{0.f,0.f,0.f,0.f}};
        floatx4 acc1[4] = {{0.f,0.f,0.f,0.f},{0.f,0.f,0.f,0.f},
                           {0.f,0.f,0.f,0.f},{0.f,0.f,0.f,0.f}};
#pragma unroll
        for (int kc = 0; kc < 4; ++kc) {
            const bf16x8 a0k = a0[kc], a1k = a1[kc];
#pragma unroll
            for (int s = 0; s < 4; ++s) {
                bf16x8 b = *reinterpret_cast<const bf16x8*>(
                    &lds[((sg0 + s) * 4 + kc) * 512 + lane * 8]);
                acc0[s] = __builtin_amdgcn_mfma_f32_16x16x32_bf16(a0k, b, acc0[s], 0, 0, 0);
                acc1[s] = __builtin_amdgcn_mfma_f32_16x16x32_bf16(a1k, b, acc1[s], 0, 0, 0);
            }
        }

        // ---- epilogue: exp and accumulate -------------------------------
#pragma unroll
        for (int s = 0; s < 4; ++s) {
            const int jj = colbase + (sg0 + s) * 16 + m;
            if (bmask) {
#pragma unroll
                for (int r = 0; r < 4; ++r) {
                    float e0 = EXP2F(fmaf(acc0[s][r], C_EXP, -C_EXP));
                    float e1 = EXP2F(fmaf(acc1[s][r], C_EXP, -C_EXP));
                    if (((jj ^ (i0 + r)) & ~B_HALF) == 0) e0 = 0.f;
                    if (((jj ^ (i0 + 16 + r)) & ~B_HALF) == 0) e1 = 0.f;
                    l0[r] += e0;
                    l1[r] += e1;
                }
            } else {
#pragma unroll
                for (int r = 0; r < 4; ++r) {
                    l0[r] += EXP2F(fmaf(acc0[s][r], C_EXP, -C_EXP));
                    l1[r] += EXP2F(fmaf(acc1[s][r], C_EXP, -C_EXP));
                }
            }
        }
        __syncthreads();   // all waves done reading before next stage
    }

    // ---- per-row column reduction + one atomic per row ------------------
#pragma unroll
    for (int r = 0; r < 4; ++r) {
        float s = l0[r];
        s += __shfl_xor(s, 1, 64);
        s += __shfl_xor(s, 2, 64);
        s += __shfl_xor(s, 4, 64);
        s += __shfl_xor(s, 8, 64);
        if (m == 0) atomicAdd(&l_arr[i0 + r], s);
    }
#pragma unroll
    for (int r = 0; r < 4; ++r) {
        float s = l1[r];
        s += __shfl_xor(s, 1, 64);
        s += __shfl_xor(s, 2, 64);
        s += __shfl_xor(s, 4, 64);
        s += __shfl_xor(s, 8, 64);
        if (m == 0) atomicAdd(&l_arr[i0 + 16 + r], s);
    }

    // ---- last-finishing block reduces the loss --------------------------
    __threadfence();
    if (threadIdx.x == 0) {
        unsigned int old = atomicAdd(counter, 1u);
        s_last = (old == GRID_TOTAL - 1);
    }
    __syncthreads();
    if (s_last) {
        float s = 0.f;
#pragma unroll
        for (int k = 0; k < TWO_B / 256; ++k) {
            int i = threadIdx.x + k * 256;
            float lv = __hip_atomic_load(&l_arr[i], __ATOMIC_RELAXED,
                                         __HIP_MEMORY_SCOPE_AGENT);
            s += FIXED_MAX + LOG2F(lv) * 0.6931471805599453f - picked[i];
        }
#pragma unroll
        for (int off = 32; off >= 1; off >>= 1) s += __shfl_xor(s, off, 64);
        if ((threadIdx.x & 63) == 0) sred[threadIdx.x >> 6] = s;
        __syncthreads();
        if (threadIdx.x == 0)
            out[0] = (sred[0] + sred[1] + sred[2] + sred[3]) * (1.0f / TWO_B);
    }
}

extern "C" void kernel_launch(void* const* d_in, const int* in_sizes, int n_in,
                              void* d_out, int out_size, void* d_ws, size_t ws_size,
                              hipStream_t stream) {
    const float* emb    = (const float*)d_in[0];
    const int*   labels = (const int*)d_in[1];
    char* ws = (char*)d_ws;
    // ws layout: l_arr[8192] f32 | picked[8192] f32 | counter | nb bf16[8192*128]
    float*        l_arr   = (float*)ws;
    float*        picked  = (float*)(ws + 32768);
    unsigned int* counter = (unsigned int*)(ws + 65536);
    __bf16*       nb      = (__bf16*)(ws + 65792);
    float*        out     = (float*)d_out;

    k_prep<<<TWO_B / 4, 256, 0, stream>>>(emb, labels, nb, picked, l_arr, counter);
    dim3 g2(NROWBLK, NSPLIT);
    k_fused<<<g2, 256, 0, stream>>>(nb, l_arr, picked, counter, out);
}

// Round 6
// 91.575 us; speedup vs baseline: 2.5628x; 2.5628x over previous
//
#include <hip/hip_runtime.h>
#include <hip/hip_bf16.h>

// NT-Xent loss, 2B=8192, D=128, T=0.5. THREE dispatches, NO device fences:
//  k_prep : row-normalize -> bf16 nb; picked logit per row (fp32); zero l_arr.
//  k_gemm : Gram matrix via MFMA, B staged in LDS (global_load_lds w=16),
//           masked exp-sum (fixed max=2.0, cos<=1) -> one atomic per row.
//  k_final: 1 block reduces 2 + ln(l_arr[i]) - picked[i] -> loss.
// Round-6 insight: the per-block __threadfence() (rounds 3-5) emits a
// cross-XCD L2 writeback on gfx950 — ~80-90 ns serialized per block, which
// was ~85% of k_fused's runtime. Kernel boundaries give coherence for free.

typedef __bf16 bf16x8 __attribute__((ext_vector_type(8)));
typedef float floatx4 __attribute__((ext_vector_type(4)));

#define TWO_B 8192
#define B_HALF 4096
#define D 128
#define INV_T 2.0f                 // 1/temperature
#define FIXED_MAX 2.0f             // logit upper bound (cos<=1)
#define C_EXP 2.885390081777927f   // INV_T * log2(e) == FIXED_MAX * log2(e)
#define NSPLIT 16                  // column splits (512 cols each)
#define NROWBLK (TWO_B / 128)      // 64 row blocks (128 rows each)

#if defined(__has_builtin) && __has_builtin(__builtin_amdgcn_exp2f)
#define EXP2F(x) __builtin_amdgcn_exp2f(x)   // raw v_exp_f32; arg in [-5.8, 0]
#else
#define EXP2F(x) exp2f(x)
#endif
#if defined(__has_builtin) && __has_builtin(__builtin_amdgcn_logf)
#define LOG2F(x) __builtin_amdgcn_logf(x)    // raw v_log_f32 (log2)
#else
#define LOG2F(x) log2f(x)
#endif

__device__ inline void load16_lds(const __bf16* g, __bf16* l) {
    __builtin_amdgcn_global_load_lds(
        (const __attribute__((address_space(1))) unsigned int*)g,
        (__attribute__((address_space(3))) unsigned int*)l, 16, 0, 0);
}

// -------- kernel 1: normalize + picked + zero l_arr ----------------------
__global__ void k_prep(const float* __restrict__ emb,
                       const int* __restrict__ labels,
                       __bf16* __restrict__ nb,
                       float* __restrict__ picked,
                       float* __restrict__ l_arr) {
    int wv   = threadIdx.x >> 6;
    int lane = threadIdx.x & 63;
    int i = blockIdx.x * 4 + wv;
    const float2* e2 = reinterpret_cast<const float2*>(emb + (size_t)i * D);
    float2 v = e2[lane];
    float ssi = v.x * v.x + v.y * v.y;
    // picked column: labels[i] skips cols {i, i^4096}
    int p = i ^ B_HALF;
    int a = min(i, p), b = max(i, p);
    int l = labels[i];
    int c = l + (l >= a);
    c += (c >= b);
    const float2* ec2 = reinterpret_cast<const float2*>(emb + (size_t)c * D);
    float2 u = ec2[lane];
    float dot = v.x * u.x + v.y * u.y;
    float ssc = u.x * u.x + u.y * u.y;
#pragma unroll
    for (int off = 32; off >= 1; off >>= 1) {
        ssi += __shfl_xor(ssi, off, 64);
        dot += __shfl_xor(dot, off, 64);
        ssc += __shfl_xor(ssc, off, 64);
    }
    float rn = rsqrtf(fmaxf(ssi, 1e-16f));
    union { __bf16 h[2]; unsigned int uu; } pk;
    pk.h[0] = (__bf16)(v.x * rn);
    pk.h[1] = (__bf16)(v.y * rn);
    reinterpret_cast<unsigned int*>(nb)[i * 64 + lane] = pk.uu;
    if (lane == 0)
        picked[i] = dot / fmaxf(sqrtf(ssi * ssc), 1e-8f) * INV_T;
    if (blockIdx.x < TWO_B / 256) l_arr[blockIdx.x * 256 + threadIdx.x] = 0.f;
}

// -------- kernel 2: fused Gram MFMA + masked exp-sum ---------------------
// grid (64, 16), block 256 = 4 waves. Block tile: 128 rows x 512 cols,
// processed as 4 chunks of 128 cols staged in LDS (fragment order).
// Each wave: 32 rows x full chunk, 8 independent MFMA chains per group.
__global__ __launch_bounds__(256, 4) void k_gemm(const __bf16* __restrict__ nb,
                                                 float* __restrict__ l_arr) {
    __shared__ __bf16 lds[16384];            // 32 KB: 128 cols x K=128

    const int lane = threadIdx.x & 63;
    const int w    = threadIdx.x >> 6;
    const int m    = lane & 15;
    const int quad = lane >> 4;
    const int row0 = blockIdx.x * 128 + w * 32;   // wave rows: row0..row0+31
    const int colB = blockIdx.y * 512;            // block cols

    // block-uniform: does this tile contain masked (diag/positive) entries?
    const int r0 = blockIdx.x * 128;
    const int pr0 = r0 ^ B_HALF;
    const bool bmask = ((r0 < colB + 512) && (colB < r0 + 128)) ||
                       ((pr0 < colB + 512) && (colB < pr0 + 128));

    // A fragments: two 16-row tiles, full K=128, pinned in registers (32 VGPR)
    bf16x8 a0[4], a1[4];
#pragma unroll
    for (int kc = 0; kc < 4; ++kc) {
        a0[kc] = *reinterpret_cast<const bf16x8*>(
            nb + (size_t)(row0 + m) * D + kc * 32 + quad * 8);
        a1[kc] = *reinterpret_cast<const bf16x8*>(
            nb + (size_t)(row0 + 16 + m) * D + kc * 32 + quad * 8);
    }
    // opaque to the register allocator: forbids rematerializing the loads
    asm volatile("" : "+v"(a0[0]), "+v"(a0[1]), "+v"(a0[2]), "+v"(a0[3]),
                      "+v"(a1[0]), "+v"(a1[1]), "+v"(a1[2]), "+v"(a1[3]));

    float l0[4] = {0.f, 0.f, 0.f, 0.f};
    float l1[4] = {0.f, 0.f, 0.f, 0.f};
    const int i0 = row0 + quad * 4;          // l0 rows; l1 rows = i0+16

    for (int ch = 0; ch < 4; ++ch) {
        const int colbase = colB + ch * 128;
        // ---- stage 128 cols x 128 K into LDS, fragment order ------------
        // instr j by wave w -> sub-tile s=j, kc=w slice
        {
            const __bf16* g = nb + (size_t)(colbase + m) * D + w * 32 + quad * 8;
#pragma unroll
            for (int j = 0; j < 8; ++j)
                load16_lds(g + (size_t)j * 16 * D, &lds[j * 2048 + w * 512]);
        }
        __syncthreads();   // compiler drains vmcnt(0) before barrier

        // ---- two groups of 4 sub-tiles; 8 independent chains each -------
#pragma unroll
        for (int grp = 0; grp < 2; ++grp) {
            floatx4 acc0[4] = {{0.f,0.f,0.f,0.f},{0.f,0.f,0.f,0.f},
                               {0.f,0.f,0.f,0.f},{0.f,0.f,0.f,0.f}};
            floatx4 acc1[4] = {{0.f,0.f,0.f,0.f},{0.f,0.f,0.f,0.f},
                               {0.f,0.f,0.f,0.f},{0.f,0.f,0.f,0.f}};
#pragma unroll
            for (int kc = 0; kc < 4; ++kc) {
                const bf16x8 a0k = a0[kc], a1k = a1[kc];
#pragma unroll
                for (int s = 0; s < 4; ++s) {
                    bf16x8 b = *reinterpret_cast<const bf16x8*>(
                        &lds[((grp * 4 + s) * 4 + kc) * 512 + lane * 8]);
                    acc0[s] = __builtin_amdgcn_mfma_f32_16x16x32_bf16(a0k, b, acc0[s], 0, 0, 0);
                    acc1[s] = __builtin_amdgcn_mfma_f32_16x16x32_bf16(a1k, b, acc1[s], 0, 0, 0);
                }
            }
            // ---- epilogue: exp and accumulate ---------------------------
#pragma unroll
            for (int s = 0; s < 4; ++s) {
                const int jj = colbase + (grp * 4 + s) * 16 + m;
                if (bmask) {
#pragma unroll
                    for (int r = 0; r < 4; ++r) {
                        float e0 = EXP2F(fmaf(acc0[s][r], C_EXP, -C_EXP));
                        float e1 = EXP2F(fmaf(acc1[s][r], C_EXP, -C_EXP));
                        if (((jj ^ (i0 + r)) & ~B_HALF) == 0) e0 = 0.f;
                        if (((jj ^ (i0 + 16 + r)) & ~B_HALF) == 0) e1 = 0.f;
                        l0[r] += e0;
                        l1[r] += e1;
                    }
                } else {
#pragma unroll
                    for (int r = 0; r < 4; ++r) {
                        l0[r] += EXP2F(fmaf(acc0[s][r], C_EXP, -C_EXP));
                        l1[r] += EXP2F(fmaf(acc1[s][r], C_EXP, -C_EXP));
                    }
                }
            }
        }
        __syncthreads();   // all waves done reading before next stage
    }

    // ---- per-row column reduction + one atomic per row ------------------
#pragma unroll
    for (int r = 0; r < 4; ++r) {
        float s = l0[r];
        s += __shfl_xor(s, 1, 64);
        s += __shfl_xor(s, 2, 64);
        s += __shfl_xor(s, 4, 64);
        s += __shfl_xor(s, 8, 64);
        if (m == 0) atomicAdd(&l_arr[i0 + r], s);
    }
#pragma unroll
    for (int r = 0; r < 4; ++r) {
        float s = l1[r];
        s += __shfl_xor(s, 1, 64);
        s += __shfl_xor(s, 2, 64);
        s += __shfl_xor(s, 4, 64);
        s += __shfl_xor(s, 8, 64);
        if (m == 0) atomicAdd(&l_arr[i0 + 16 + r], s);
    }
}

// -------- kernel 3: single-block final reduce ----------------------------
__global__ void k_final(const float* __restrict__ l_arr,
                        const float* __restrict__ picked,
                        float* __restrict__ out) {
    __shared__ float sred[4];
    float s = 0.f;
#pragma unroll
    for (int k = 0; k < TWO_B / 256; ++k) {
        int i = threadIdx.x + k * 256;
        s += FIXED_MAX + LOG2F(l_arr[i]) * 0.6931471805599453f - picked[i];
    }
#pragma unroll
    for (int off = 32; off >= 1; off >>= 1) s += __shfl_xor(s, off, 64);
    if ((threadIdx.x & 63) == 0) sred[threadIdx.x >> 6] = s;
    __syncthreads();
    if (threadIdx.x == 0)
        out[0] = (sred[0] + sred[1] + sred[2] + sred[3]) * (1.0f / TWO_B);
}

extern "C" void kernel_launch(void* const* d_in, const int* in_sizes, int n_in,
                              void* d_out, int out_size, void* d_ws, size_t ws_size,
                              hipStream_t stream) {
    const float* emb    = (const float*)d_in[0];
    const int*   labels = (const int*)d_in[1];
    char* ws = (char*)d_ws;
    // ws layout: l_arr[8192] f32 | picked[8192] f32 | nb bf16[8192*128]
    float*  l_arr  = (float*)ws;
    float*  picked = (float*)(ws + 32768);
    __bf16* nb     = (__bf16*)(ws + 65536);
    float*  out    = (float*)d_out;

    k_prep<<<TWO_B / 4, 256, 0, stream>>>(emb, labels, nb, picked, l_arr);
    dim3 g2(NROWBLK, NSPLIT);
    k_gemm<<<g2, 256, 0, stream>>>(nb, l_arr);
    k_final<<<1, 256, 0, stream>>>(l_arr, picked, out);
}

// Round 7
// 84.009 us; speedup vs baseline: 2.7936x; 1.0901x over previous
//
#include <hip/hip_runtime.h>
#include <hip/hip_bf16.h>

// NT-Xent loss, 2B=8192, D=128, T=0.5. THREE dispatches, NO device fences:
//  k_prep : row-normalize -> bf16 nb; picked logit per row (fp32); zero l_arr.
//  k_gemm : SYMMETRIC Gram: only upper-triangle 128x128 block tiles
//           (circulant pairing bj=(bi+by)&63, by in [0,32]). Each off-diag
//           tile's exp values feed BOTH l[row] (row-sum) and l[col]
//           (col-sum: quad shuffles + LDS cross-wave reduce + atomics).
//           Fixed softmax max = 2.0 (cos<=1). B staged in LDS, w=16.
//  k_final: 1 block reduces 2 + ln(l_arr[i]) - picked[i] -> loss.

typedef __bf16 bf16x8 __attribute__((ext_vector_type(8)));
typedef float floatx4 __attribute__((ext_vector_type(4)));

#define TWO_B 8192
#define B_HALF 4096
#define D 128
#define INV_T 2.0f                 // 1/temperature
#define FIXED_MAX 2.0f             // logit upper bound (cos<=1)
#define C_EXP 2.885390081777927f   // INV_T * log2(e) == FIXED_MAX * log2(e)

#if defined(__has_builtin) && __has_builtin(__builtin_amdgcn_exp2f)
#define EXP2F(x) __builtin_amdgcn_exp2f(x)   // raw v_exp_f32; arg in [-5.8, 0]
#else
#define EXP2F(x) exp2f(x)
#endif
#if defined(__has_builtin) && __has_builtin(__builtin_amdgcn_logf)
#define LOG2F(x) __builtin_amdgcn_logf(x)    // raw v_log_f32 (log2)
#else
#define LOG2F(x) log2f(x)
#endif

__device__ inline void load16_lds(const __bf16* g, __bf16* l) {
    __builtin_amdgcn_global_load_lds(
        (const __attribute__((address_space(1))) unsigned int*)g,
        (__attribute__((address_space(3))) unsigned int*)l, 16, 0, 0);
}

// -------- kernel 1: normalize + picked + zero l_arr ----------------------
__global__ void k_prep(const float* __restrict__ emb,
                       const int* __restrict__ labels,
                       __bf16* __restrict__ nb,
                       float* __restrict__ picked,
                       float* __restrict__ l_arr) {
    int wv   = threadIdx.x >> 6;
    int lane = threadIdx.x & 63;
    int i = blockIdx.x * 4 + wv;
    const float2* e2 = reinterpret_cast<const float2*>(emb + (size_t)i * D);
    float2 v = e2[lane];
    float ssi = v.x * v.x + v.y * v.y;
    // picked column: labels[i] skips cols {i, i^4096}
    int p = i ^ B_HALF;
    int a = min(i, p), b = max(i, p);
    int l = labels[i];
    int c = l + (l >= a);
    c += (c >= b);
    const float2* ec2 = reinterpret_cast<const float2*>(emb + (size_t)c * D);
    float2 u = ec2[lane];
    float dot = v.x * u.x + v.y * u.y;
    float ssc = u.x * u.x + u.y * u.y;
#pragma unroll
    for (int off = 32; off >= 1; off >>= 1) {
        ssi += __shfl_xor(ssi, off, 64);
        dot += __shfl_xor(dot, off, 64);
        ssc += __shfl_xor(ssc, off, 64);
    }
    float rn = rsqrtf(fmaxf(ssi, 1e-16f));
    union { __bf16 h[2]; unsigned int uu; } pk;
    pk.h[0] = (__bf16)(v.x * rn);
    pk.h[1] = (__bf16)(v.y * rn);
    reinterpret_cast<unsigned int*>(nb)[i * 64 + lane] = pk.uu;
    if (lane == 0)
        picked[i] = dot / fmaxf(sqrtf(ssi * ssc), 1e-8f) * INV_T;
    if (blockIdx.x < TWO_B / 256) l_arr[blockIdx.x * 256 + threadIdx.x] = 0.f;
}

// -------- kernel 2: symmetric Gram MFMA + masked exp-sum -----------------
// grid (64, 33), block 256 = 4 waves. Tile: rows bi*128, cols ((bi+by)&63)*128.
// by==0: diagonal tile (row sums only). by==32 & bi>=32: duplicate, skip.
// Off-diag tiles also emit column sums (symmetry: sim(i,j)==sim(j,i)).
__global__ __launch_bounds__(256, 4) void k_gemm(const __bf16* __restrict__ nb,
                                                 float* __restrict__ l_arr) {
    __shared__ __bf16 lds[16384];            // 32 KB: 128 cols x K=128

    const int bi = blockIdx.x;
    const int by = blockIdx.y;
    if (by == 32 && bi >= 32) return;        // circulant duplicate
    const int bj = (bi + by) & 63;
    const int R0 = bi * 128;
    const int C0 = bj * 128;
    const bool isdiag = (by == 0);
    // masked entries present iff diagonal (j==i) or positive-pair (by==32)
    const bool bmask = isdiag || (by == 32);

    const int lane = threadIdx.x & 63;
    const int w    = threadIdx.x >> 6;
    const int m    = lane & 15;
    const int quad = lane >> 4;
    const int row0 = R0 + w * 32;            // wave rows: row0..row0+31

    // A fragments: two 16-row tiles, full K=128, pinned in registers
    bf16x8 a0[4], a1[4];
#pragma unroll
    for (int kc = 0; kc < 4; ++kc) {
        a0[kc] = *reinterpret_cast<const bf16x8*>(
            nb + (size_t)(row0 + m) * D + kc * 32 + quad * 8);
        a1[kc] = *reinterpret_cast<const bf16x8*>(
            nb + (size_t)(row0 + 16 + m) * D + kc * 32 + quad * 8);
    }
    asm volatile("" : "+v"(a0[0]), "+v"(a0[1]), "+v"(a0[2]), "+v"(a0[3]),
                      "+v"(a1[0]), "+v"(a1[1]), "+v"(a1[2]), "+v"(a1[3]));

    // ---- stage 128 cols x 128 K into LDS, fragment order ----------------
    {
        const __bf16* g = nb + (size_t)(C0 + m) * D + w * 32 + quad * 8;
#pragma unroll
        for (int j = 0; j < 8; ++j)
            load16_lds(g + (size_t)j * 16 * D, &lds[j * 2048 + w * 512]);
    }
    __syncthreads();   // compiler drains vmcnt(0) before barrier

    float l0[4] = {0.f, 0.f, 0.f, 0.f};
    float l1[4] = {0.f, 0.f, 0.f, 0.f};
    float csum[8];                           // per-subtile column sums
    const int i0 = row0 + quad * 4;          // l0 rows; l1 rows = i0+16

    // ---- two groups of 4 sub-tiles; 8 independent MFMA chains each ------
#pragma unroll
    for (int grp = 0; grp < 2; ++grp) {
        floatx4 acc0[4] = {{0.f,0.f,0.f,0.f},{0.f,0.f,0.f,0.f},
                           {0.f,0.f,0.f,0.f},{0.f,0.f,0.f,0.f}};
        floatx4 acc1[4] = {{0.f,0.f,0.f,0.f},{0.f,0.f,0.f,0.f},
                           {0.f,0.f,0.f,0.f},{0.f,0.f,0.f,0.f}};
#pragma unroll
        for (int kc = 0; kc < 4; ++kc) {
            const bf16x8 a0k = a0[kc], a1k = a1[kc];
#pragma unroll
            for (int s = 0; s < 4; ++s) {
                bf16x8 b = *reinterpret_cast<const bf16x8*>(
                    &lds[((grp * 4 + s) * 4 + kc) * 512 + lane * 8]);
                acc0[s] = __builtin_amdgcn_mfma_f32_16x16x32_bf16(a0k, b, acc0[s], 0, 0, 0);
                acc1[s] = __builtin_amdgcn_mfma_f32_16x16x32_bf16(a1k, b, acc1[s], 0, 0, 0);
            }
        }
        // ---- epilogue: exp, row-accumulate, col-accumulate --------------
#pragma unroll
        for (int s = 0; s < 4; ++s) {
            const int jj = C0 + (grp * 4 + s) * 16 + m;
            float cs = 0.f;
            if (bmask) {
#pragma unroll
                for (int r = 0; r < 4; ++r) {
                    float e0 = EXP2F(fmaf(acc0[s][r], C_EXP, -C_EXP));
                    float e1 = EXP2F(fmaf(acc1[s][r], C_EXP, -C_EXP));
                    if (((jj ^ (i0 + r)) & ~B_HALF) == 0) e0 = 0.f;
                    if (((jj ^ (i0 + 16 + r)) & ~B_HALF) == 0) e1 = 0.f;
                    l0[r] += e0;
                    l1[r] += e1;
                    cs += e0 + e1;
                }
            } else {
#pragma unroll
                for (int r = 0; r < 4; ++r) {
                    float e0 = EXP2F(fmaf(acc0[s][r], C_EXP, -C_EXP));
                    float e1 = EXP2F(fmaf(acc1[s][r], C_EXP, -C_EXP));
                    l0[r] += e0;
                    l1[r] += e1;
                    cs += e0 + e1;
                }
            }
            // full 32-row column sum for col jj (sum across quads)
            cs += __shfl_xor(cs, 16, 64);
            cs += __shfl_xor(cs, 32, 64);
            csum[grp * 4 + s] = cs;
        }
    }

    // ---- per-row reduction + one atomic per row -------------------------
#pragma unroll
    for (int r = 0; r < 4; ++r) {
        float s = l0[r];
        s += __shfl_xor(s, 1, 64);
        s += __shfl_xor(s, 2, 64);
        s += __shfl_xor(s, 4, 64);
        s += __shfl_xor(s, 8, 64);
        if (m == 0) atomicAdd(&l_arr[i0 + r], s);
    }
#pragma unroll
    for (int r = 0; r < 4; ++r) {
        float s = l1[r];
        s += __shfl_xor(s, 1, 64);
        s += __shfl_xor(s, 2, 64);
        s += __shfl_xor(s, 4, 64);
        s += __shfl_xor(s, 8, 64);
        if (m == 0) atomicAdd(&l_arr[i0 + 16 + r], s);
    }

    // ---- column sums (off-diagonal tiles only): cross-wave via LDS ------
    if (!isdiag) {
        __syncthreads();                     // B reads done; reuse LDS
        float* ldsf = reinterpret_cast<float*>(lds);
        if (quad == 0) {                     // lanes 0..15 hold csum
#pragma unroll
            for (int sub = 0; sub < 8; ++sub)
                ldsf[w * 128 + sub * 16 + m] = csum[sub];
        }
        __syncthreads();
        if (threadIdx.x < 128) {
            float t = ldsf[threadIdx.x] + ldsf[128 + threadIdx.x] +
                      ldsf[256 + threadIdx.x] + ldsf[384 + threadIdx.x];
            atomicAdd(&l_arr[C0 + threadIdx.x], t);
        }
    }
}

// -------- kernel 3: single-block final reduce ----------------------------
__global__ void k_final(const float* __restrict__ l_arr,
                        const float* __restrict__ picked,
                        float* __restrict__ out) {
    __shared__ float sred[4];
    float s = 0.f;
#pragma unroll
    for (int k = 0; k < TWO_B / 256; ++k) {
        int i = threadIdx.x + k * 256;
        s += FIXED_MAX + LOG2F(l_arr[i]) * 0.6931471805599453f - picked[i];
    }
#pragma unroll
    for (int off = 32; off >= 1; off >>= 1) s += __shfl_xor(s, off, 64);
    if ((threadIdx.x & 63) == 0) sred[threadIdx.x >> 6] = s;
    __syncthreads();
    if (threadIdx.x == 0)
        out[0] = (sred[0] + sred[1] + sred[2] + sred[3]) * (1.0f / TWO_B);
}

extern "C" void kernel_launch(void* const* d_in, const int* in_sizes, int n_in,
                              void* d_out, int out_size, void* d_ws, size_t ws_size,
                              hipStream_t stream) {
    const float* emb    = (const float*)d_in[0];
    const int*   labels = (const int*)d_in[1];
    char* ws = (char*)d_ws;
    // ws layout: l_arr[8192] f32 | picked[8192] f32 | nb bf16[8192*128]
    float*  l_arr  = (float*)ws;
    float*  picked = (float*)(ws + 32768);
    __bf16* nb     = (__bf16*)(ws + 65536);
    float*  out    = (float*)d_out;

    k_prep<<<TWO_B / 4, 256, 0, stream>>>(emb, labels, nb, picked, l_arr);
    dim3 g2(64, 33);
    k_gemm<<<g2, 256, 0, stream>>>(nb, l_arr);
    k_final<<<1, 256, 0, stream>>>(l_arr, picked, out);
}

// Round 8
// 83.090 us; speedup vs baseline: 2.8245x; 1.0111x over previous
//
#include <hip/hip_runtime.h>
#include <hip/hip_bf16.h>

// NT-Xent loss, 2B=8192, D=128, T=0.5. THREE dispatches, NO device fences:
//  k_prep : row-normalize -> bf16 nb; picked logit per row (fp32); zero l_arr.
//  k_gemm : SYMMETRIC Gram, upper-triangle 128x128 tiles via circulant
//           pairing bj=(bi+by)&63, by in [0,32]. Each block handles TWO
//           strips {g, g+17} for one row-block: A fragments loaded once,
//           row sums accumulated in registers across both tiles (atomics
//           once), per-tile column sums via LDS cross-wave reduce.
//           Fixed softmax max = 2.0 (cos<=1). B staged in LDS, w=16.
//  k_final: 1 block (1024 thr) reduces 2 + ln(l_arr[i]) - picked[i].

typedef __bf16 bf16x8 __attribute__((ext_vector_type(8)));
typedef float floatx4 __attribute__((ext_vector_type(4)));

#define TWO_B 8192
#define B_HALF 4096
#define D 128
#define INV_T 2.0f                 // 1/temperature
#define FIXED_MAX 2.0f             // logit upper bound (cos<=1)
#define C_EXP 2.885390081777927f   // INV_T * log2(e) == FIXED_MAX * log2(e)

#if defined(__has_builtin) && __has_builtin(__builtin_amdgcn_exp2f)
#define EXP2F(x) __builtin_amdgcn_exp2f(x)   // raw v_exp_f32; arg in [-5.8, 0]
#else
#define EXP2F(x) exp2f(x)
#endif
#if defined(__has_builtin) && __has_builtin(__builtin_amdgcn_logf)
#define LOG2F(x) __builtin_amdgcn_logf(x)    // raw v_log_f32 (log2)
#else
#define LOG2F(x) log2f(x)
#endif

__device__ inline void load16_lds(const __bf16* g, __bf16* l) {
    __builtin_amdgcn_global_load_lds(
        (const __attribute__((address_space(1))) unsigned int*)g,
        (__attribute__((address_space(3))) unsigned int*)l, 16, 0, 0);
}

// -------- kernel 1: normalize + picked + zero l_arr ----------------------
__global__ void k_prep(const float* __restrict__ emb,
                       const int* __restrict__ labels,
                       __bf16* __restrict__ nb,
                       float* __restrict__ picked,
                       float* __restrict__ l_arr) {
    int wv   = threadIdx.x >> 6;
    int lane = threadIdx.x & 63;
    int i = blockIdx.x * 4 + wv;
    const float2* e2 = reinterpret_cast<const float2*>(emb + (size_t)i * D);
    float2 v = e2[lane];
    float ssi = v.x * v.x + v.y * v.y;
    // picked column: labels[i] skips cols {i, i^4096}
    int p = i ^ B_HALF;
    int a = min(i, p), b = max(i, p);
    int l = labels[i];
    int c = l + (l >= a);
    c += (c >= b);
    const float2* ec2 = reinterpret_cast<const float2*>(emb + (size_t)c * D);
    float2 u = ec2[lane];
    float dot = v.x * u.x + v.y * u.y;
    float ssc = u.x * u.x + u.y * u.y;
#pragma unroll
    for (int off = 32; off >= 1; off >>= 1) {
        ssi += __shfl_xor(ssi, off, 64);
        dot += __shfl_xor(dot, off, 64);
        ssc += __shfl_xor(ssc, off, 64);
    }
    float rn = rsqrtf(fmaxf(ssi, 1e-16f));
    union { __bf16 h[2]; unsigned int uu; } pk;
    pk.h[0] = (__bf16)(v.x * rn);
    pk.h[1] = (__bf16)(v.y * rn);
    reinterpret_cast<unsigned int*>(nb)[i * 64 + lane] = pk.uu;
    if (lane == 0)
        picked[i] = dot / fmaxf(sqrtf(ssi * ssc), 1e-8f) * INV_T;
    if (blockIdx.x < TWO_B / 256) l_arr[blockIdx.x * 256 + threadIdx.x] = 0.f;
}

// -------- kernel 2: symmetric Gram MFMA + masked exp-sum -----------------
// grid (64, 17), block 256 = 4 waves. Block (bi,g): rows bi*128, strips
// by in {g, g+17} (by<=32; by==32 only valid for bi<32; by==0 = diagonal).
__global__ __launch_bounds__(256, 4) void k_gemm(const __bf16* __restrict__ nb,
                                                 float* __restrict__ l_arr) {
    __shared__ __bf16 lds[16384];            // 32 KB: 128 cols x K=128

    const int bi = blockIdx.x;
    const int g  = blockIdx.y;

    const int lane = threadIdx.x & 63;
    const int w    = threadIdx.x >> 6;
    const int m    = lane & 15;
    const int quad = lane >> 4;
    const int row0 = bi * 128 + w * 32;      // wave rows: row0..row0+31

    // A fragments: two 16-row tiles, full K=128, pinned, loaded ONCE
    bf16x8 a0[4], a1[4];
#pragma unroll
    for (int kc = 0; kc < 4; ++kc) {
        a0[kc] = *reinterpret_cast<const bf16x8*>(
            nb + (size_t)(row0 + m) * D + kc * 32 + quad * 8);
        a1[kc] = *reinterpret_cast<const bf16x8*>(
            nb + (size_t)(row0 + 16 + m) * D + kc * 32 + quad * 8);
    }
    asm volatile("" : "+v"(a0[0]), "+v"(a0[1]), "+v"(a0[2]), "+v"(a0[3]),
                      "+v"(a1[0]), "+v"(a1[1]), "+v"(a1[2]), "+v"(a1[3]));

    float l0[4] = {0.f, 0.f, 0.f, 0.f};      // row sums, carried across strips
    float l1[4] = {0.f, 0.f, 0.f, 0.f};
    const int i0 = row0 + quad * 4;          // l0 rows; l1 rows = i0+16

    bool first = true;
#pragma unroll
    for (int si = 0; si < 2; ++si) {
        const int by = g + si * 17;
        if (by > 32) continue;               // g==16 has a single strip
        if (by == 32 && bi >= 32) continue;  // circulant duplicate
        const int bj = (bi + by) & 63;
        const int C0 = bj * 128;
        const bool isdiag = (by == 0);
        const bool bmask = isdiag || (by == 32);

        if (!first) __syncthreads();         // prior LDS readers done
        first = false;

        // ---- stage 128 cols x 128 K into LDS, fragment order ------------
        {
            const __bf16* gp = nb + (size_t)(C0 + m) * D + w * 32 + quad * 8;
#pragma unroll
            for (int j = 0; j < 8; ++j)
                load16_lds(gp + (size_t)j * 16 * D, &lds[j * 2048 + w * 512]);
        }
        __syncthreads();   // compiler drains vmcnt(0) before barrier

        float csum[8];                       // per-subtile column sums
        // ---- two groups of 4 sub-tiles; 8 independent MFMA chains -------
#pragma unroll
        for (int grp = 0; grp < 2; ++grp) {
            floatx4 acc0[4] = {{0.f,0.f,0.f,0.f},{0.f,0.f,0.f,0.f},
                               {0.f,0.f,0.f,0.f},{0.f,0.f,0.f,0.f}};
            floatx4 acc1[4] = {{0.f,0.f,0.f,0.f},{0.f,0.f,0.f,0.f},
                               {0.f,0.f,0.f,0.f},{0.f,0.f,0.f,0.f}};
#pragma unroll
            for (int kc = 0; kc < 4; ++kc) {
                const bf16x8 a0k = a0[kc], a1k = a1[kc];
#pragma unroll
                for (int s = 0; s < 4; ++s) {
                    bf16x8 b = *reinterpret_cast<const bf16x8*>(
                        &lds[((grp * 4 + s) * 4 + kc) * 512 + lane * 8]);
                    acc0[s] = __builtin_amdgcn_mfma_f32_16x16x32_bf16(a0k, b, acc0[s], 0, 0, 0);
                    acc1[s] = __builtin_amdgcn_mfma_f32_16x16x32_bf16(a1k, b, acc1[s], 0, 0, 0);
                }
            }
            // ---- epilogue: exp, row-accumulate, col-accumulate ----------
#pragma unroll
            for (int s = 0; s < 4; ++s) {
                const int jj = C0 + (grp * 4 + s) * 16 + m;
                float cs = 0.f;
                if (bmask) {
#pragma unroll
                    for (int r = 0; r < 4; ++r) {
                        float e0 = EXP2F(fmaf(acc0[s][r], C_EXP, -C_EXP));
                        float e1 = EXP2F(fmaf(acc1[s][r], C_EXP, -C_EXP));
                        if (((jj ^ (i0 + r)) & ~B_HALF) == 0) e0 = 0.f;
                        if (((jj ^ (i0 + 16 + r)) & ~B_HALF) == 0) e1 = 0.f;
                        l0[r] += e0;
                        l1[r] += e1;
                        cs += e0 + e1;
                    }
                } else {
#pragma unroll
                    for (int r = 0; r < 4; ++r) {
                        float e0 = EXP2F(fmaf(acc0[s][r], C_EXP, -C_EXP));
                        float e1 = EXP2F(fmaf(acc1[s][r], C_EXP, -C_EXP));
                        l0[r] += e0;
                        l1[r] += e1;
                        cs += e0 + e1;
                    }
                }
                // full 32-row column sum for col jj (sum across quads)
                cs += __shfl_xor(cs, 16, 64);
                cs += __shfl_xor(cs, 32, 64);
                csum[grp * 4 + s] = cs;
            }
        }

        // ---- column sums (off-diagonal tiles only) ----------------------
        if (!isdiag) {
            __syncthreads();                 // B reads done; reuse LDS
            float* ldsf = reinterpret_cast<float*>(lds);
            if (quad == 0) {                 // lanes 0..15 hold csum
#pragma unroll
                for (int sub = 0; sub < 8; ++sub)
                    ldsf[w * 128 + sub * 16 + m] = csum[sub];
            }
            __syncthreads();
            if (threadIdx.x < 128) {
                float t = ldsf[threadIdx.x] + ldsf[128 + threadIdx.x] +
                          ldsf[256 + threadIdx.x] + ldsf[384 + threadIdx.x];
                atomicAdd(&l_arr[C0 + threadIdx.x], t);
            }
        }
    }

    // ---- per-row reduction + one atomic per row (once per block) --------
#pragma unroll
    for (int r = 0; r < 4; ++r) {
        float s = l0[r];
        s += __shfl_xor(s, 1, 64);
        s += __shfl_xor(s, 2, 64);
        s += __shfl_xor(s, 4, 64);
        s += __shfl_xor(s, 8, 64);
        if (m == 0) atomicAdd(&l_arr[i0 + r], s);
    }
#pragma unroll
    for (int r = 0; r < 4; ++r) {
        float s = l1[r];
        s += __shfl_xor(s, 1, 64);
        s += __shfl_xor(s, 2, 64);
        s += __shfl_xor(s, 4, 64);
        s += __shfl_xor(s, 8, 64);
        if (m == 0) atomicAdd(&l_arr[i0 + 16 + r], s);
    }
}

// -------- kernel 3: single-block final reduce (1024 threads) -------------
__global__ void k_final(const float* __restrict__ l_arr,
                        const float* __restrict__ picked,
                        float* __restrict__ out) {
    __shared__ float sred[16];
    float s = 0.f;
#pragma unroll
    for (int k = 0; k < TWO_B / 1024; ++k) {
        int i = threadIdx.x + k * 1024;
        s += FIXED_MAX + LOG2F(l_arr[i]) * 0.6931471805599453f - picked[i];
    }
#pragma unroll
    for (int off = 32; off >= 1; off >>= 1) s += __shfl_xor(s, off, 64);
    if ((threadIdx.x & 63) == 0) sred[threadIdx.x >> 6] = s;
    __syncthreads();
    if (threadIdx.x == 0) {
        float t = 0.f;
#pragma unroll
        for (int k = 0; k < 16; ++k) t += sred[k];
        out[0] = t * (1.0f / TWO_B);
    }
}

extern "C" void kernel_launch(void* const* d_in, const int* in_sizes, int n_in,
                              void* d_out, int out_size, void* d_ws, size_t ws_size,
                              hipStream_t stream) {
    const float* emb    = (const float*)d_in[0];
    const int*   labels = (const int*)d_in[1];
    char* ws = (char*)d_ws;
    // ws layout: l_arr[8192] f32 | picked[8192] f32 | nb bf16[8192*128]
    float*  l_arr  = (float*)ws;
    float*  picked = (float*)(ws + 32768);
    __bf16* nb     = (__bf16*)(ws + 65536);
    float*  out    = (float*)d_out;

    k_prep<<<TWO_B / 4, 256, 0, stream>>>(emb, labels, nb, picked, l_arr);
    dim3 g2(64, 17);
    k_gemm<<<g2, 256, 0, stream>>>(nb, l_arr);
    k_final<<<1, 1024, 0, stream>>>(l_arr, picked, out);
}